// Round 4
// baseline (1020.950 us; speedup 1.0000x reference)
//
#include <hip/hip_runtime.h>
#include <hip/hip_bf16.h>
#include <math.h>

#define N_ENT   50000
#define N_REL   237
#define N_TYPE  4000
#define DE      100
#define NOUT    128
#define DT      200
#define N_EDGE  800000
#define B_SZ    4096
#define ALPHA   0.2f
#define EPS     1e-5f
#define NUM_FILT 32
#define CONV_W_OUT 60
#define POOL_W  30
#define FC_LEN  960
#define KP      224
#define NTP     4032   // logits N padded to 63*64
#define EBCAP   96     // max edges per slot (Poisson(16), max deg ~45 in 4k slots)
#define MEGA_BLOCKS 512

typedef unsigned short ushort_t;
typedef __attribute__((ext_vector_type(8))) short bf16x8;
typedef __attribute__((ext_vector_type(4))) float f32x4;

// ---------------- diagnostic fill (f32) ----------------
__global__ void k_fillconst(float* p, long n, float val) {
    long i = (long)blockIdx.x * blockDim.x + threadIdx.x;
    long stride = (long)gridDim.x * blockDim.x;
    for (; i < n; i += stride) p[i] = val;
}

// ------- merged: zero-fill (blocks 0..57) || wa1/wa2/rw precompute (block 58) -------
#define ZERO_F4 14676   // 234,816 B = counter+gbar state+flags+slotent+ecount+sums
__global__ void k_fillprep(float4* zp, const float* Wf, const float* a_vec,
                           const float* Rw, float* wa1, float* wa2, float* rw) {
    if (blockIdx.x < 58) {
        int i = blockIdx.x * 256 + threadIdx.x;
        if (i < ZERO_F4) zp[i] = make_float4(0.f, 0.f, 0.f, 0.f);
        return;
    }
    __shared__ float sa[2 * NOUT];
    __shared__ float swa2[DE];
    int t = threadIdx.x;
    sa[t] = a_vec[t];
    __syncthreads();
    if (t < DE) {
        float s1 = 0.f, s2 = 0.f;
        for (int j = 0; j < NOUT; j++) {
            float w = Wf[t * NOUT + j];
            s1 += w * sa[j];
            s2 += w * sa[NOUT + j];
        }
        wa1[t] = s1; wa2[t] = s2; swa2[t] = s2;
    }
    __syncthreads();
    if (t < N_REL) {
        float s = 0.f;
        for (int k = 0; k < DE; k++) s += Rw[t * DE + k] * swa2[k];
        rw[t] = s;
    }
}

// ---------------- device-scope grid barrier (co-residency guaranteed by launch_bounds) ----------------
__device__ __forceinline__ void gbar(int* cnt, int* gen) {
    __threadfence();          // publish this block's writes (L2 writeback at agent scope)
    __syncthreads();
    if (threadIdx.x == 0) {
        int g = __hip_atomic_load(gen, __ATOMIC_RELAXED, __HIP_MEMORY_SCOPE_AGENT);
        int v = __hip_atomic_fetch_add(cnt, 1, __ATOMIC_ACQ_REL, __HIP_MEMORY_SCOPE_AGENT);
        if (v == (int)gridDim.x - 1) {
            __hip_atomic_store(cnt, 0, __ATOMIC_RELAXED, __HIP_MEMORY_SCOPE_AGENT);
            __hip_atomic_store(gen, g + 1, __ATOMIC_RELEASE, __HIP_MEMORY_SCOPE_AGENT);
        } else {
            while (__hip_atomic_load(gen, __ATOMIC_RELAXED, __HIP_MEMORY_SCOPE_AGENT) == g)
                __builtin_amdgcn_s_sleep(2);
        }
    }
    __syncthreads();
    __threadfence();          // invalidate stale cached lines before next phase reads
}

// ---------------- mega kernel: flags -> slots/entdots -> scatter -> agg ->
//                  gatherconv -> redAB -> pool + bfc repack (6 grid barriers) ----------------
__launch_bounds__(256, 4)
__global__ void k_mega(const int* xb, const int* ei, const int* et,
                       const float* Ew, const float* Rw, const float* Wf,
                       const float* convw, const float* g1, const float* g3,
                       const float* b3, const float* fcw,
                       int* flags, int* counter, int* slotent, int* ecount,
                       const float* wa1, const float* wa2, const float* rw,
                       float* ha, float* ewd, float* ebuf, float* gps, float* gpq,
                       float* cpart, float* AB, float* aggc, int2* ebuck,
                       __hip_bfloat16* pooled, __hip_bfloat16* bfc,
                       int* cnt, int* gen) {
    __shared__ float smem[1256];
    int t = threadIdx.x;
    int nb = gridDim.x;

    // ---- P1: batch membership flags ----
    for (int vb = blockIdx.x; vb < 16; vb += nb) {
        int i = vb * 256 + t;
        if (i < B_SZ) flags[xb[i]] = 1;
    }
    gbar(cnt, gen);

    // ---- P2: compact slots || per-entity dots ----
    for (int vb = blockIdx.x; vb < 12696; vb += nb) {
        if (vb < 196) {
            int i = vb * 256 + t;
            if (i < N_ENT && flags[i]) {
                int s = atomicAdd(counter, 1);
                flags[i] = 1 + s;
                slotent[s] = i;
            }
        } else {
            int wid = (vb - 196) * 4 + (t >> 6);
            int lane = t & 63;
            if (wid < N_ENT) {
                float s1 = 0.f, s2 = 0.f;
                if (lane < DE / 2) {
                    const float2* p = (const float2*)(Ew + (size_t)wid * DE);
                    float2 v = p[lane];
                    s1 = v.x * wa1[2 * lane] + v.y * wa1[2 * lane + 1];
                    s2 = v.x * wa2[2 * lane] + v.y * wa2[2 * lane + 1];
                }
                for (int off = 32; off > 0; off >>= 1) {
                    s1 += __shfl_down(s1, off);
                    s2 += __shfl_down(s2, off);
                }
                if (lane == 0) { ha[wid] = s1; ewd[wid] = s2; }
            }
        }
    }
    gbar(cnt, gen);

    // ---- P3: single-pass bucket scatter ----
    for (int vb = blockIdx.x; vb < 3125; vb += nb) {
        int e = vb * 256 + t;
        if (e < N_EDGE) {
            int s = flags[ei[N_EDGE + e]];
            if (s) {
                int idx = atomicAdd(&ecount[s - 1], 1);
                if (idx < EBCAP)
                    ebuck[(size_t)(s - 1) * EBCAP + idx] = make_int2(ei[e], et[e]);
            }
        }
    }
    gbar(cnt, gen);

    // ---- P4: per-slot softmax-weighted aggregation (2-way edge split) ----
    {
        int nslot = counter[0];
        int half = t >> 7, tl = t & 127;
        float* sacc = smem;
        float* sden = smem + 128;
        for (int slot = blockIdx.x; slot < B_SZ; slot += nb) {
            bool act = slot < nslot;
            float acc = 0.f, den = 0.f;
            if (act) {
                int n = min(ecount[slot], EBCAP);
                const int2* eb = ebuck + (size_t)slot * EBCAP;
                float hae = ha[slotent[slot]];
                for (int j = half; j < n; j += 2) {
                    int2 p = eb[j];
                    float sc = hae + ewd[p.x] - rw[p.y];
                    sc = sc >= 0.f ? sc : ALPHA * sc;
                    float ex = expf(sc);
                    den += ex;
                    if (tl < DE)
                        acc += ex * (Ew[(size_t)p.x * DE + tl] - Rw[(size_t)p.y * DE + tl]);
                }
            }
            if (act && half == 1) {
                if (tl < DE) sacc[tl] = acc;
                if (tl == 0) sden[0] = den;
            }
            __syncthreads();
            if (act && half == 0 && tl < DE)
                aggc[(size_t)slot * DE + tl] = (acc + sacc[tl]) / (den + sden[0] + 1e-16f);
            __syncthreads();
        }
    }
    gbar(cnt, gen);

    // ---- P5: gather + project + elu + conv-u partial stats (two halves/block) ----
    {
        int half = t >> 7, tl = t & 127;
        float* row  = smem;            // [2][100]
        float* xs   = smem + 200;      // [2][128]
        float* cw   = smem + 456;      // [288]
        float* red  = smem + 744;      // [2][128]
        float* red2 = smem + 1000;     // [2][128]
        for (int vb = blockIdx.x; vb < B_SZ / 2; vb += nb) {
            int b = vb * 2 + half;
            int slot = flags[xb[b]] - 1;
            if (tl < DE) row[half * DE + tl] = aggc[(size_t)slot * DE + tl];
            for (int i = t; i < 288; i += 256) cw[i] = convw[i];
            __syncthreads();
            float acc = 0.f;
            for (int k = 0; k < DE; k++) acc += row[half * DE + k] * Wf[k * NOUT + tl];
            float x = acc > 0.f ? acc : expm1f(acc);
            xs[half * NOUT + tl] = x;
            ebuf[(size_t)b * NOUT + tl] = x;
            red[half * NOUT + tl] = x; red2[half * NOUT + tl] = x * x;
            __syncthreads();
            for (int s = 64; s > 0; s >>= 1) {
                if (tl < s) {
                    red[half * NOUT + tl]  += red[half * NOUT + tl + s];
                    red2[half * NOUT + tl] += red2[half * NOUT + tl + s];
                }
                __syncthreads();
            }
            if (tl == 0) { gps[b] = red[half * NOUT]; gpq[b] = red2[half * NOUT]; }
            int c = tl >> 2, wg = tl & 3;
            float ls = 0.f, lq = 0.f;
            for (int i2 = 0; i2 < 15; i2++) {
                int w = wg + 4 * i2;
                float u = 0.f;
                #pragma unroll
                for (int j = 0; j < 9; j++) u += cw[c * 9 + j] * xs[half * NOUT + 2 * w + j];
                ls += u; lq += u * u;
            }
            __syncthreads();
            red[half * NOUT + tl] = ls; red2[half * NOUT + tl] = lq;
            __syncthreads();
            if (wg == 0) {
                float s = red[half*NOUT+tl] + red[half*NOUT+tl+1] + red[half*NOUT+tl+2] + red[half*NOUT+tl+3];
                float q = red2[half*NOUT+tl] + red2[half*NOUT+tl+1] + red2[half*NOUT+tl+2] + red2[half*NOUT+tl+3];
                cpart[b * 64 + c] = s;
                cpart[b * 64 + 32 + c] = q;
            }
            __syncthreads();
        }
    }
    gbar(cnt, gen);

    // ---- P6: stat reductions -> A_c, B_c (32 blocks) ----
    {
        float* r1 = smem;       float* r2 = smem + 256;
        float* r3 = smem + 512; float* r4 = smem + 768;
        for (int c = blockIdx.x; c < 32; c += nb) {
            float s = 0.f, q = 0.f, cs = 0.f, cq = 0.f;
            for (int b = t; b < B_SZ; b += 256) {
                s += gps[b]; q += gpq[b];
                cs += cpart[b * 64 + c]; cq += cpart[b * 64 + 32 + c];
            }
            r1[t] = s; r2[t] = q; r3[t] = cs; r4[t] = cq;
            __syncthreads();
            for (int k = 128; k > 0; k >>= 1) {
                if (t < k) { r1[t] += r1[t+k]; r2[t] += r2[t+k]; r3[t] += r3[t+k]; r4[t] += r4[t+k]; }
                __syncthreads();
            }
            if (t == 0) {
                float N1 = (float)(B_SZ * NOUT);
                float m1 = r1[0] / N1;
                float v1 = r2[0] / N1 - m1 * m1;
                float s1 = g1[0] * rsqrtf(v1 + EPS);
                float Nc = (float)(B_SZ * CONV_W_OUT);
                float mu = r3[0] / Nc;
                float vu = r4[0] / Nc - mu * mu;
                float A = g3[c] * s1 * rsqrtf(s1 * s1 * vu + EPS);
                AB[c] = A;
                AB[32 + c] = b3[c] - A * mu;
            }
            __syncthreads();
        }
    }
    gbar(cnt, gen);

    // ---- P7: conv recompute + affine + relu + pool (two halves) + bfc repack ----
    {
        int half = t >> 7, tl = t & 127;
        float* xs  = smem;        // [2][128]
        float* cw  = smem + 256;  // [288]
        float* sAB = smem + 544;  // [64]
        for (int vb = blockIdx.x; vb < B_SZ / 2; vb += nb) {
            int b = vb * 2 + half;
            xs[half * NOUT + tl] = ebuf[(size_t)b * NOUT + tl];
            for (int i = t; i < 288; i += 256) cw[i] = convw[i];
            if (t < 64) sAB[t] = AB[t];
            __syncthreads();
            int c = tl >> 2, wg = tl & 3;
            float A = sAB[c], Bv = sAB[32 + c];
            for (int i2 = 0; i2 < 8; i2++) {
                int w2 = wg + 4 * i2;
                if (w2 < POOL_W) {
                    int w = 2 * w2;
                    float u0 = 0.f, u1 = 0.f;
                    #pragma unroll
                    for (int j = 0; j < 9; j++) {
                        float cv = cw[c * 9 + j];
                        u0 += cv * xs[half * NOUT + 2 * w + j];
                        u1 += cv * xs[half * NOUT + 2 * w + 2 + j];
                    }
                    float z0 = fmaxf(A * u0 + Bv, 0.f);
                    float z1 = fmaxf(A * u1 + Bv, 0.f);
                    pooled[((size_t)b * NUM_FILT + c) * POOL_W + w2] = __float2bfloat16(fmaxf(z0, z1));
                }
            }
            __syncthreads();
        }
        for (int i = blockIdx.x * 256 + t; i < KP * FC_LEN; i += nb * 256)
            bfc[i] = __float2bfloat16((i < DT * FC_LEN) ? fcw[i] : 0.f);
    }
}

// ---------------- MFMA GEMM, swapped-operand transposed epilogue ----------------
// mfma(b, a, acc): lane&15 = output ROW, (lane>>4)*4+reg = 4 contiguous output COLS.
// MODE 0: C = A@B^T + bias (f32) + bn2 stats atomics into sums[448];
//         blockIdx.y >= 7 strips do the T_w -> b2 bf16 repack instead.
// MODE 1: sigmoid(A@B^T + bias), store guard cc < nbias.
template<int MODE, int K, int NB>
__launch_bounds__(256, 4)
__global__ void k_gemm(const ushort_t* A, const ushort_t* Bm, const float* bias,
                       int ldc, int nbias, float* Cf, float* sums,
                       const float* tw, __hip_bfloat16* b2pad) {
    if constexpr (MODE == 0) {
        if (blockIdx.y >= 7) {   // b2 repack strip
            int pid = (blockIdx.y - 7) * 32 + blockIdx.x;
            int jj = pid * 256 + (int)threadIdx.x;
            if (jj < NTP * KP) {
                int n = jj / KP, k = jj - n * KP;
                float v = (n < N_TYPE && k < DT) ? tw[n * DT + k] : 0.f;
                b2pad[jj] = __float2bfloat16(v);
            }
            return;
        }
    }
    int wave = threadIdx.x >> 6, lane = threadIdx.x & 63;
    int m0 = blockIdx.x * 128 + wave * 32;
    int n0 = blockIdx.y * (16 * NB);
    int rsel = lane & 15, ksel = (lane >> 4) * 8;
    const ushort_t* pa0 = A + (size_t)(m0 + rsel) * K + ksel;
    const ushort_t* pa1 = pa0 + (size_t)16 * K;
    const ushort_t* pb[NB];
    #pragma unroll
    for (int j = 0; j < NB; j++) pb[j] = Bm + (size_t)(n0 + j * 16 + rsel) * K + ksel;
    f32x4 acc0[NB], acc1[NB];
    #pragma unroll
    for (int j = 0; j < NB; j++) { acc0[j] = (f32x4){0.f,0.f,0.f,0.f}; acc1[j] = acc0[j]; }
    if constexpr (K <= 256) {
        #pragma unroll
        for (int k = 0; k < K; k += 32) {
            bf16x8 a0 = *(const bf16x8*)(pa0 + k);
            bf16x8 a1 = *(const bf16x8*)(pa1 + k);
            #pragma unroll
            for (int j = 0; j < NB; j++) {
                bf16x8 b = *(const bf16x8*)(pb[j] + k);
                acc0[j] = __builtin_amdgcn_mfma_f32_16x16x32_bf16(b, a0, acc0[j], 0, 0, 0);
                acc1[j] = __builtin_amdgcn_mfma_f32_16x16x32_bf16(b, a1, acc1[j], 0, 0, 0);
            }
        }
    } else {
        #pragma unroll 4
        for (int k = 0; k < K; k += 32) {
            bf16x8 a0 = *(const bf16x8*)(pa0 + k);
            bf16x8 a1 = *(const bf16x8*)(pa1 + k);
            #pragma unroll
            for (int j = 0; j < NB; j++) {
                bf16x8 b = *(const bf16x8*)(pb[j] + k);
                acc0[j] = __builtin_amdgcn_mfma_f32_16x16x32_bf16(b, a0, acc0[j], 0, 0, 0);
                acc1[j] = __builtin_amdgcn_mfma_f32_16x16x32_bf16(b, a1, acc1[j], 0, 0, 0);
            }
        }
    }
    int mloc = lane & 15;
    int nq = (lane >> 4) * 4;
    #pragma unroll
    for (int j = 0; j < NB; j++) {
        int cc = n0 + j * 16 + nq;
        if (cc < nbias) {
            float4 bb = *(const float4*)(bias + cc);
            f32x4 v0 = acc0[j], v1 = acc1[j];
            float4 r0, r1;
            if (MODE == 0) {
                r0 = make_float4(v0[0] + bb.x, v0[1] + bb.y, v0[2] + bb.z, v0[3] + bb.w);
                r1 = make_float4(v1[0] + bb.x, v1[1] + bb.y, v1[2] + bb.z, v1[3] + bb.w);
            } else {
                r0.x = __builtin_amdgcn_rcpf(1.f + __expf(-(v0[0] + bb.x)));
                r0.y = __builtin_amdgcn_rcpf(1.f + __expf(-(v0[1] + bb.y)));
                r0.z = __builtin_amdgcn_rcpf(1.f + __expf(-(v0[2] + bb.z)));
                r0.w = __builtin_amdgcn_rcpf(1.f + __expf(-(v0[3] + bb.w)));
                r1.x = __builtin_amdgcn_rcpf(1.f + __expf(-(v1[0] + bb.x)));
                r1.y = __builtin_amdgcn_rcpf(1.f + __expf(-(v1[1] + bb.y)));
                r1.z = __builtin_amdgcn_rcpf(1.f + __expf(-(v1[2] + bb.z)));
                r1.w = __builtin_amdgcn_rcpf(1.f + __expf(-(v1[3] + bb.w)));
            }
            *(float4*)(Cf + (size_t)(m0 + mloc) * ldc + cc) = r0;
            *(float4*)(Cf + (size_t)(m0 + 16 + mloc) * ldc + cc) = r1;
            if (MODE == 0) {
                // bn2 partial stats: reduce over the 16 rows held across mloc lanes
                float s0 = r0.x + r1.x, s1 = r0.y + r1.y, s2 = r0.z + r1.z, s3 = r0.w + r1.w;
                float q0 = r0.x*r0.x + r1.x*r1.x, q1 = r0.y*r0.y + r1.y*r1.y;
                float q2 = r0.z*r0.z + r1.z*r1.z, q3 = r0.w*r0.w + r1.w*r1.w;
                #pragma unroll
                for (int off = 1; off <= 8; off <<= 1) {
                    s0 += __shfl_xor(s0, off); s1 += __shfl_xor(s1, off);
                    s2 += __shfl_xor(s2, off); s3 += __shfl_xor(s3, off);
                    q0 += __shfl_xor(q0, off); q1 += __shfl_xor(q1, off);
                    q2 += __shfl_xor(q2, off); q3 += __shfl_xor(q3, off);
                }
                if (mloc == 0) {
                    atomicAdd(&sums[cc + 0], s0); atomicAdd(&sums[cc + 1], s1);
                    atomicAdd(&sums[cc + 2], s2); atomicAdd(&sums[cc + 3], s3);
                    atomicAdd(&sums[KP + cc + 0], q0); atomicAdd(&sums[KP + cc + 1], q1);
                    atomicAdd(&sums[KP + cc + 2], q2); atomicAdd(&sums[KP + cc + 3], q3);
                }
            }
        }
    }
}

// ------- bn2 apply + relu -> bf16 A2 [B,224]; scale/shift derived inline -------
__global__ void k_bn2apply(const float* fcout, const float* sums,
                           const float* g, const float* bb, __hip_bfloat16* a2) {
    int i = blockIdx.x * blockDim.x + threadIdx.x;
    if (i >= B_SZ * KP) return;
    int t = i % KP;
    float v = 0.f;
    if (t < DT) {
        float mean = sums[t] * (1.f / B_SZ);
        float var = sums[KP + t] * (1.f / B_SZ) - mean * mean;
        float sc = g[t] * rsqrtf(var + EPS);
        float sh = bb[t] - mean * sc;
        v = fcout[i] * sc + sh;
        v = fmaxf(v, 0.f);
    }
    a2[i] = __float2bfloat16(v);
}

extern "C" void kernel_launch(void* const* d_in, const int* in_sizes, int n_in,
                              void* d_out, int out_size, void* d_ws, size_t ws_size,
                              hipStream_t stream) {
    (void)in_sizes; (void)n_in;
    const int*   x_batch = (const int*)d_in[0];
    const int*   ei      = (const int*)d_in[1];
    const int*   etype   = (const int*)d_in[2];
    const float* E_w     = (const float*)d_in[3];
    const float* R_w     = (const float*)d_in[4];
    const float* T_w     = (const float*)d_in[5];
    const float* W_f     = (const float*)d_in[6];
    const float* a_vec   = (const float*)d_in[7];
    const float* conv_w  = (const float*)d_in[8];
    const float* bn1_g   = (const float*)d_in[10];
    const float* bn3_g   = (const float*)d_in[12];
    const float* bn3_b   = (const float*)d_in[13];
    const float* bn2_g   = (const float*)d_in[14];
    const float* bn2_b   = (const float*)d_in[15];
    const float* fc_w    = (const float*)d_in[16];
    const float* fc_b    = (const float*)d_in[17];
    const float* b_bias  = (const float*)d_in[18];
    float* out           = (float*)d_out;
    long outn = (long)out_size;

    const size_t WS_NEEDED = 4279296;
    if (ws_size < WS_NEEDED) {
        k_fillconst<<<2048, 256, 0, stream>>>(out, outn, 50.f);
        return;
    }
    char* ws = (char*)d_ws;
    float* wa1      = (float*)(ws + 0);
    float* wa2      = (float*)(ws + 512);
    float* rw       = (float*)(ws + 1024);
    float* AB       = (float*)(ws + 2048);       // A[0..31], B[32..63]
    float* gps      = (float*)(ws + 4864);       // [4096]
    float* gpq      = (float*)(ws + 21248);      // [4096]
    float* cpart    = (float*)(ws + 37632);      // [4096][64] -> ends 1,086,208
    int*   counter  = (int*)  (ws + 1086208);    // zero-region start
    int*   gcnt     = (int*)  (ws + 1086216);    // grid-barrier count
    int*   ggen     = (int*)  (ws + 1086220);    // grid-barrier generation
    int*   flags    = (int*)  (ws + 1086464);    // [50000]
    int*   slotent  = (int*)  (ws + 1286464);    // [4096]
    int*   ecount   = (int*)  (ws + 1302848);    // [4096] -> ends 1,319,232
    float* sums     = (float*)(ws + 1319232);    // [448] bn2 accum -> zero-region ends 1,321,024
    float* ha       = (float*)(ws + 1352064);    // [50000]
    float* ew       = (float*)(ws + 1552064);    // [50000]
    float* ebuf     = (float*)(ws + 1752064);    // [4096,128] f32 -> ends 3,849,216
    __hip_bfloat16* bfc = (__hip_bfloat16*)(ws + 3849216);   // [224,960] -> ends 4,279,296
    // late-phase overlays (prior occupants dead):
    __hip_bfloat16* a2 = (__hip_bfloat16*)(ws + 4864);       // [4096,224] -> ends 1,839,872
    __hip_bfloat16* b2 = (__hip_bfloat16*)(ws + 1840128);    // [4032,224] -> ends 3,646,464
    // d_out scratch (65.5 MB; final GEMM reads only ws, rewrites all of d_out)
    __hip_bfloat16* pooled = (__hip_bfloat16*)((char*)d_out + 0);        // 7.86 MB
    float* fcout    = (float*)((char*)d_out + 8388608);                  // 3.67 MB
    int2*  ebuck    = (int2*) ((char*)d_out + 16777216);                 // 4096*96*8 = 3.1 MB
    float* aggc     = (float*)((char*)d_out + 25165824);                 // 1.6 MB

    // 1. zero {counter,gbar,flags,slotent,ecount,sums} || rank-1 precompute
    k_fillprep<<<59, 256, 0, stream>>>((float4*)counter, W_f, a_vec, R_w, wa1, wa2, rw);
    // 2. mega: flags -> slots/entdots -> scatter -> agg -> gatherconv -> redAB -> pool+bfc
    k_mega<<<MEGA_BLOCKS, 256, 0, stream>>>(
        x_batch, ei, etype, E_w, R_w, W_f, conv_w, bn1_g, bn3_g, bn3_b, fc_w,
        flags, counter, slotent, ecount, wa1, wa2, rw, ha, ew, ebuf,
        gps, gpq, cpart, AB, aggc, ebuck, pooled, bfc, gcnt, ggen);
    // 3. FC GEMM (y<7) + b2 repack (y>=7) + bn2 stats atomics
    k_gemm<0, FC_LEN, 2><<<dim3(32, 118), 256, 0, stream>>>(
        (const ushort_t*)pooled, (const ushort_t*)bfc, fc_b, KP, DT, fcout,
        sums, T_w, b2);
    // 4. bn2 apply (scale/shift inline)
    k_bn2apply<<<3584, 256, 0, stream>>>(fcout, sums, bn2_g, bn2_b, a2);
    // 5. logits GEMM + sigmoid
    k_gemm<1, KP, 4><<<dim3(32, 63), 256, 0, stream>>>(
        (const ushort_t*)a2, (const ushort_t*)b2, b_bias, N_TYPE, N_TYPE, out,
        nullptr, nullptr, nullptr);
}

// Round 5
// 308.502 us; speedup vs baseline: 3.3094x; 3.3094x over previous
//
#include <hip/hip_runtime.h>
#include <hip/hip_bf16.h>
#include <math.h>

#define N_ENT   50000
#define N_REL   237
#define N_TYPE  4000
#define DE      100
#define NOUT    128
#define DT      200
#define N_EDGE  800000
#define B_SZ    4096
#define ALPHA   0.2f
#define EPS     1e-5f
#define NUM_FILT 32
#define CONV_W_OUT 60
#define POOL_W  30
#define FC_LEN  960
#define KP      224
#define NTP     4032   // logits N padded to 63*64
#define EBCAP   96     // max edges per slot (Poisson(16), max deg ~45 in 4k slots)

typedef unsigned short ushort_t;
typedef __attribute__((ext_vector_type(8))) short bf16x8;
typedef __attribute__((ext_vector_type(4))) float f32x4;

// ---------------- diagnostic fill (f32) ----------------
__global__ void k_fillconst(float* p, long n, float val) {
    long i = (long)blockIdx.x * blockDim.x + threadIdx.x;
    long stride = (long)gridDim.x * blockDim.x;
    for (; i < n; i += stride) p[i] = val;
}

// ------- merged: zero-fill (blocks 0..57) || wa1/wa2/rw precompute (block 58) -------
#define ZERO_F4 14676   // 234,816 B = counter+pad+flags+slotent+ecount+sums
__global__ void k_fillprep(float4* zp, const float* Wf, const float* a_vec,
                           const float* Rw, float* wa1, float* wa2, float* rw) {
    if (blockIdx.x < 58) {
        int i = blockIdx.x * 256 + threadIdx.x;
        if (i < ZERO_F4) zp[i] = make_float4(0.f, 0.f, 0.f, 0.f);
        return;
    }
    __shared__ float sa[2 * NOUT];
    __shared__ float swa2[DE];
    int t = threadIdx.x;
    sa[t] = a_vec[t];
    __syncthreads();
    if (t < DE) {
        float s1 = 0.f, s2 = 0.f;
        for (int j = 0; j < NOUT; j++) {
            float w = Wf[t * NOUT + j];
            s1 += w * sa[j];
            s2 += w * sa[NOUT + j];
        }
        wa1[t] = s1; wa2[t] = s2; swa2[t] = s2;
    }
    __syncthreads();
    if (t < N_REL) {
        float s = 0.f;
        for (int k = 0; k < DE; k++) s += Rw[t * DE + k] * swa2[k];
        rw[t] = s;
    }
}

// ---------------- batch membership flags ----------------
__global__ void k_flags(const int* xb, int* flags) {
    int i = blockIdx.x * blockDim.x + threadIdx.x;
    if (i < B_SZ) flags[xb[i]] = 1;
}

// ------- merged: compact slots (blocks 0..195) || per-entity dots (blocks 196..) -------
__global__ void k_slotsent(int* flags, int* counter, int* slotent,
                           const float* Ew, const float* wa1, const float* wa2,
                           float* ha, float* ew) {
    if (blockIdx.x < 196) {
        int i = blockIdx.x * 256 + threadIdx.x;
        if (i >= N_ENT) return;
        if (flags[i]) {
            int s = atomicAdd(counter, 1);
            flags[i] = 1 + s;
            slotent[s] = i;
        }
        return;
    }
    int wid = (blockIdx.x - 196) * 4 + (threadIdx.x >> 6);
    int lane = threadIdx.x & 63;
    if (wid >= N_ENT) return;
    float s1 = 0.f, s2 = 0.f;
    if (lane < DE / 2) {
        const float2* p = (const float2*)(Ew + (size_t)wid * DE);
        float2 v = p[lane];
        s1 = v.x * wa1[2 * lane] + v.y * wa1[2 * lane + 1];
        s2 = v.x * wa2[2 * lane] + v.y * wa2[2 * lane + 1];
    }
    for (int off = 32; off > 0; off >>= 1) {
        s1 += __shfl_down(s1, off);
        s2 += __shfl_down(s2, off);
    }
    if (lane == 0) { ha[wid] = s1; ew[wid] = s2; }
}

// ------- single-pass scatter into fixed-capacity buckets -------
__global__ void k_scatter96(const int* ei, const int* et, const int* flags,
                            int* ecount, int2* ebuck) {
    int e = blockIdx.x * blockDim.x + threadIdx.x;
    if (e >= N_EDGE) return;
    int s = flags[ei[N_EDGE + e]];
    if (!s) return;
    int idx = atomicAdd(&ecount[s - 1], 1);
    if (idx < EBCAP)
        ebuck[(size_t)(s - 1) * EBCAP + idx] = make_int2(ei[e], et[e]);
}

// ------- per-slot aggregation: 2 halves process alternate edges (halved serial chain) -------
__global__ void k_agg(const int* counter, const int* ecount, const int* slotent,
                      const int2* ebuck, const float* Ew, const float* Rw,
                      const float* ha, const float* ew, const float* rw,
                      float* aggc) {
    __shared__ float sacc[DE];
    __shared__ float sden;
    int slot = blockIdx.x;
    if (slot >= counter[0]) return;
    int t = threadIdx.x;          // 256
    int half = t >> 7;            // 0 or 1
    int tl = t & 127;
    int n = min(ecount[slot], EBCAP);
    const int2* eb = ebuck + (size_t)slot * EBCAP;
    float hae = ha[slotent[slot]];
    float acc = 0.f, den = 0.f;
    for (int j = half; j < n; j += 2) {
        int2 p = eb[j];
        float sc = hae + ew[p.x] - rw[p.y];
        sc = sc >= 0.f ? sc : ALPHA * sc;
        float ex = expf(sc);
        den += ex;
        if (tl < DE) acc += ex * (Ew[(size_t)p.x * DE + tl] - Rw[(size_t)p.y * DE + tl]);
    }
    if (half == 1) {
        if (tl < DE) sacc[tl] = acc;
        if (tl == 0) sden = den;
    }
    __syncthreads();
    if (half == 0 && tl < DE) {
        float a = acc + sacc[tl];
        float d = den + sden;
        aggc[(size_t)slot * DE + tl] = a / (d + 1e-16f);
    }
}

// -------- gather + project + elu + conv-u partial stats (no atomics) --------
__global__ void k_gatherconv(const int* xb, const int* flags, const float* aggc,
                             const float* Wf, const float* convw,
                             float* ebuf, float* gps, float* gpq, float* cpart) {
    __shared__ float row[DE];
    __shared__ float xs[NOUT];
    __shared__ float cw[NUM_FILT * 9];
    __shared__ float red[NOUT], red2[NOUT];
    int b = blockIdx.x, t = threadIdx.x;
    int slot = flags[xb[b]] - 1;
    if (t < DE) row[t] = aggc[(size_t)slot * DE + t];
    for (int i = t; i < NUM_FILT * 9; i += 128) cw[i] = convw[i];
    __syncthreads();
    float acc = 0.f;
    for (int k = 0; k < DE; k++) acc += row[k] * Wf[k * NOUT + t];
    float x = acc > 0.f ? acc : expm1f(acc);
    xs[t] = x;
    ebuf[(size_t)b * NOUT + t] = x;
    red[t] = x; red2[t] = x * x;
    __syncthreads();
    for (int s = 64; s > 0; s >>= 1) {
        if (t < s) { red[t] += red[t + s]; red2[t] += red2[t + s]; }
        __syncthreads();
    }
    if (t == 0) { gps[b] = red[0]; gpq[b] = red2[0]; }
    int c = t >> 2, wg = t & 3;
    float ls = 0.f, lq = 0.f;
    for (int i = 0; i < 15; i++) {
        int w = wg + 4 * i;
        float u = 0.f;
        #pragma unroll
        for (int j = 0; j < 9; j++) u += cw[c * 9 + j] * xs[2 * w + j];
        ls += u; lq += u * u;
    }
    __syncthreads();
    red[t] = ls; red2[t] = lq;
    __syncthreads();
    if (wg == 0) {
        float s = red[t] + red[t + 1] + red[t + 2] + red[t + 3];
        float q = red2[t] + red2[t + 1] + red2[t + 2] + red2[t + 3];
        cpart[b * 64 + c] = s;
        cpart[b * 64 + 32 + c] = q;
    }
}

// ------- reduce stats per filter -> A_c, B_c -------
__global__ void k_redAB(const float* gps, const float* gpq, const float* cpart,
                        const float* g1, const float* g3, const float* b3, float* AB) {
    __shared__ float r1[256], r2[256], r3[256], r4[256];
    int c = blockIdx.x, t = threadIdx.x;
    float s = 0.f, q = 0.f, cs = 0.f, cq = 0.f;
    for (int b = t; b < B_SZ; b += 256) {
        s += gps[b]; q += gpq[b];
        cs += cpart[b * 64 + c]; cq += cpart[b * 64 + 32 + c];
    }
    r1[t] = s; r2[t] = q; r3[t] = cs; r4[t] = cq;
    __syncthreads();
    for (int k = 128; k > 0; k >>= 1) {
        if (t < k) { r1[t] += r1[t+k]; r2[t] += r2[t+k]; r3[t] += r3[t+k]; r4[t] += r4[t+k]; }
        __syncthreads();
    }
    if (t == 0) {
        float N1 = (float)(B_SZ * NOUT);
        float m1 = r1[0] / N1;
        float v1 = r2[0] / N1 - m1 * m1;
        float s1 = g1[0] * rsqrtf(v1 + EPS);
        float Nc = (float)(B_SZ * CONV_W_OUT);
        float mu = r3[0] / Nc;
        float vu = r4[0] / Nc - mu * mu;
        float A = g3[c] * s1 * rsqrtf(s1 * s1 * vu + EPS);
        AB[c] = A;
        AB[32 + c] = b3[c] - A * mu;
    }
}

// ---------------- conv recompute + fused affine + relu + pool ----------------
__global__ void k_pool(const float* ebuf, const float* convw, const float* AB,
                       __hip_bfloat16* pooled) {
    __shared__ float xs[NOUT];
    __shared__ float cw[NUM_FILT * 9];
    __shared__ float sA[32], sB[32];
    int b = blockIdx.x, t = threadIdx.x;
    xs[t] = ebuf[(size_t)b * NOUT + t];
    for (int i = t; i < NUM_FILT * 9; i += 128) cw[i] = convw[i];
    if (t < 32) { sA[t] = AB[t]; sB[t] = AB[32 + t]; }
    __syncthreads();
    int c = t >> 2, wg = t & 3;
    float A = sA[c], Bv = sB[c];
    for (int i = 0; i < 8; i++) {
        int w2 = wg + 4 * i;
        if (w2 < POOL_W) {
            int w = 2 * w2;
            float u0 = 0.f, u1 = 0.f;
            #pragma unroll
            for (int j = 0; j < 9; j++) {
                float cv = cw[c * 9 + j];
                u0 += cv * xs[2 * w + j];
                u1 += cv * xs[2 * w + 2 + j];
            }
            float z0 = fmaxf(A * u0 + Bv, 0.f);
            float z1 = fmaxf(A * u1 + Bv, 0.f);
            pooled[((size_t)b * NUM_FILT + c) * POOL_W + w2] = __float2bfloat16(fmaxf(z0, z1));
        }
    }
}

// ------- bfc repack only: fc_w -> bfc [224,960] bf16 (zero pad rows 200..223) -------
__global__ void k_padsbfc(const float* fcw, __hip_bfloat16* bfc) {
    int i = blockIdx.x * blockDim.x + threadIdx.x;
    if (i < KP * FC_LEN)
        bfc[i] = __float2bfloat16((i < DT * FC_LEN) ? fcw[i] : 0.f);
}

// ---------------- FC GEMM: BM=64 (2x blocks vs BM=128), no bias (cancels in bn2),
//                  fused bn2 stats atomics; blockIdx.y>=7 strips repack T_w -> b2 ----------------
__launch_bounds__(256, 4)
__global__ void k_gemm_fc(const ushort_t* A, const ushort_t* Bm, float* Cf,
                          float* sums, const float* tw, __hip_bfloat16* b2pad) {
    constexpr int K = FC_LEN;
    if (blockIdx.y >= 7) {   // b2 repack strip: pid in [0, 56*64)
        int pid = (blockIdx.y - 7) * 64 + blockIdx.x;
        int jj = pid * 256 + (int)threadIdx.x;
        if (jj < NTP * KP) {
            int n = jj / KP, k = jj - n * KP;
            float v = (n < N_TYPE && k < DT) ? tw[n * DT + k] : 0.f;
            b2pad[jj] = __float2bfloat16(v);
        }
        return;
    }
    int wave = threadIdx.x >> 6, lane = threadIdx.x & 63;
    int m0 = blockIdx.x * 64 + wave * 16;
    int n0 = blockIdx.y * 32;
    int rsel = lane & 15, ksel = (lane >> 4) * 8;
    const ushort_t* pa0 = A + (size_t)(m0 + rsel) * K + ksel;
    const ushort_t* pb0 = Bm + (size_t)(n0 + rsel) * K + ksel;
    const ushort_t* pb1 = pb0 + (size_t)16 * K;
    f32x4 acc0 = (f32x4){0.f,0.f,0.f,0.f}, acc1 = acc0;
    #pragma unroll 4
    for (int k = 0; k < K; k += 32) {
        bf16x8 a0 = *(const bf16x8*)(pa0 + k);
        bf16x8 b0 = *(const bf16x8*)(pb0 + k);
        bf16x8 b1 = *(const bf16x8*)(pb1 + k);
        acc0 = __builtin_amdgcn_mfma_f32_16x16x32_bf16(b0, a0, acc0, 0, 0, 0);
        acc1 = __builtin_amdgcn_mfma_f32_16x16x32_bf16(b1, a0, acc1, 0, 0, 0);
    }
    // transposed epilogue: lane owns row m0+mloc, cols cc..cc+3
    int mloc = lane & 15;
    int nq = (lane >> 4) * 4;
    #pragma unroll
    for (int j = 0; j < 2; j++) {
        int cc = n0 + j * 16 + nq;
        if (cc < DT) {
            f32x4 v = j ? acc1 : acc0;
            float4 r = make_float4(v[0], v[1], v[2], v[3]);
            *(float4*)(Cf + (size_t)(m0 + mloc) * KP + cc) = r;
            // bn2 partial stats over the 16 rows spread across mloc lanes
            float s0 = r.x, s1 = r.y, s2 = r.z, s3 = r.w;
            float q0 = r.x*r.x, q1 = r.y*r.y, q2 = r.z*r.z, q3 = r.w*r.w;
            #pragma unroll
            for (int off = 1; off <= 8; off <<= 1) {
                s0 += __shfl_xor(s0, off); s1 += __shfl_xor(s1, off);
                s2 += __shfl_xor(s2, off); s3 += __shfl_xor(s3, off);
                q0 += __shfl_xor(q0, off); q1 += __shfl_xor(q1, off);
                q2 += __shfl_xor(q2, off); q3 += __shfl_xor(q3, off);
            }
            if (mloc == 0) {
                atomicAdd(&sums[cc + 0], s0); atomicAdd(&sums[cc + 1], s1);
                atomicAdd(&sums[cc + 2], s2); atomicAdd(&sums[cc + 3], s3);
                atomicAdd(&sums[KP + cc + 0], q0); atomicAdd(&sums[KP + cc + 1], q1);
                atomicAdd(&sums[KP + cc + 2], q2); atomicAdd(&sums[KP + cc + 3], q3);
            }
        }
    }
}

// ---------------- logits GEMM + sigmoid, swapped-operand transposed epilogue ----------------
template<int K, int NB>
__launch_bounds__(256, 4)
__global__ void k_gemm_sig(const ushort_t* A, const ushort_t* Bm, const float* bias,
                           float* Cf) {
    int wave = threadIdx.x >> 6, lane = threadIdx.x & 63;
    int m0 = blockIdx.x * 128 + wave * 32;
    int n0 = blockIdx.y * (16 * NB);
    int rsel = lane & 15, ksel = (lane >> 4) * 8;
    const ushort_t* pa0 = A + (size_t)(m0 + rsel) * K + ksel;
    const ushort_t* pa1 = pa0 + (size_t)16 * K;
    const ushort_t* pb[NB];
    #pragma unroll
    for (int j = 0; j < NB; j++) pb[j] = Bm + (size_t)(n0 + j * 16 + rsel) * K + ksel;
    f32x4 acc0[NB], acc1[NB];
    #pragma unroll
    for (int j = 0; j < NB; j++) { acc0[j] = (f32x4){0.f,0.f,0.f,0.f}; acc1[j] = acc0[j]; }
    #pragma unroll
    for (int k = 0; k < K; k += 32) {
        bf16x8 a0 = *(const bf16x8*)(pa0 + k);
        bf16x8 a1 = *(const bf16x8*)(pa1 + k);
        #pragma unroll
        for (int j = 0; j < NB; j++) {
            bf16x8 b = *(const bf16x8*)(pb[j] + k);
            acc0[j] = __builtin_amdgcn_mfma_f32_16x16x32_bf16(b, a0, acc0[j], 0, 0, 0);
            acc1[j] = __builtin_amdgcn_mfma_f32_16x16x32_bf16(b, a1, acc1[j], 0, 0, 0);
        }
    }
    int mloc = lane & 15;
    int nq = (lane >> 4) * 4;
    #pragma unroll
    for (int j = 0; j < NB; j++) {
        int cc = n0 + j * 16 + nq;
        if (cc < N_TYPE) {
            float4 bb = *(const float4*)(bias + cc);
            f32x4 v0 = acc0[j], v1 = acc1[j];
            float4 r0, r1;
            r0.x = __builtin_amdgcn_rcpf(1.f + __expf(-(v0[0] + bb.x)));
            r0.y = __builtin_amdgcn_rcpf(1.f + __expf(-(v0[1] + bb.y)));
            r0.z = __builtin_amdgcn_rcpf(1.f + __expf(-(v0[2] + bb.z)));
            r0.w = __builtin_amdgcn_rcpf(1.f + __expf(-(v0[3] + bb.w)));
            r1.x = __builtin_amdgcn_rcpf(1.f + __expf(-(v1[0] + bb.x)));
            r1.y = __builtin_amdgcn_rcpf(1.f + __expf(-(v1[1] + bb.y)));
            r1.z = __builtin_amdgcn_rcpf(1.f + __expf(-(v1[2] + bb.z)));
            r1.w = __builtin_amdgcn_rcpf(1.f + __expf(-(v1[3] + bb.w)));
            *(float4*)(Cf + (size_t)(m0 + mloc) * N_TYPE + cc) = r0;
            *(float4*)(Cf + (size_t)(m0 + 16 + mloc) * N_TYPE + cc) = r1;
        }
    }
}

// ------- bn2 apply + relu -> bf16 A2 [B,224]; scale/shift derived inline -------
__global__ void k_bn2apply(const float* fcout, const float* sums,
                           const float* g, const float* bb, __hip_bfloat16* a2) {
    int i = blockIdx.x * blockDim.x + threadIdx.x;
    if (i >= B_SZ * KP) return;
    int t = i % KP;
    float v = 0.f;
    if (t < DT) {
        float mean = sums[t] * (1.f / B_SZ);
        float var = sums[KP + t] * (1.f / B_SZ) - mean * mean;
        float sc = g[t] * rsqrtf(var + EPS);
        float sh = bb[t] - mean * sc;
        v = fcout[i] * sc + sh;
        v = fmaxf(v, 0.f);
    }
    a2[i] = __float2bfloat16(v);
}

extern "C" void kernel_launch(void* const* d_in, const int* in_sizes, int n_in,
                              void* d_out, int out_size, void* d_ws, size_t ws_size,
                              hipStream_t stream) {
    (void)in_sizes; (void)n_in;
    const int*   x_batch = (const int*)d_in[0];
    const int*   ei      = (const int*)d_in[1];
    const int*   etype   = (const int*)d_in[2];
    const float* E_w     = (const float*)d_in[3];
    const float* R_w     = (const float*)d_in[4];
    const float* T_w     = (const float*)d_in[5];
    const float* W_f     = (const float*)d_in[6];
    const float* a_vec   = (const float*)d_in[7];
    const float* conv_w  = (const float*)d_in[8];
    const float* bn1_g   = (const float*)d_in[10];
    const float* bn3_g   = (const float*)d_in[12];
    const float* bn3_b   = (const float*)d_in[13];
    const float* bn2_g   = (const float*)d_in[14];
    const float* bn2_b   = (const float*)d_in[15];
    const float* fc_w    = (const float*)d_in[16];
    const float* b_bias  = (const float*)d_in[18];
    float* out           = (float*)d_out;
    long outn = (long)out_size;

    const size_t WS_NEEDED = 4279296;
    if (ws_size < WS_NEEDED) {
        k_fillconst<<<2048, 256, 0, stream>>>(out, outn, 50.f);
        return;
    }
    char* ws = (char*)d_ws;
    float* wa1      = (float*)(ws + 0);
    float* wa2      = (float*)(ws + 512);
    float* rw       = (float*)(ws + 1024);
    float* AB       = (float*)(ws + 2048);       // A[0..31], B[32..63]
    float* gps      = (float*)(ws + 4864);       // [4096]
    float* gpq      = (float*)(ws + 21248);      // [4096]
    float* cpart    = (float*)(ws + 37632);      // [4096][64] -> ends 1,086,208
    int*   counter  = (int*)  (ws + 1086208);    // zero-region start
    int*   flags    = (int*)  (ws + 1086464);    // [50000]
    int*   slotent  = (int*)  (ws + 1286464);    // [4096]
    int*   ecount   = (int*)  (ws + 1302848);    // [4096] -> ends 1,319,232
    float* sums     = (float*)(ws + 1319232);    // [448] bn2 accum -> zero-region ends 1,321,024
    float* ha       = (float*)(ws + 1352064);    // [50000]
    float* ew       = (float*)(ws + 1552064);    // [50000]
    float* ebuf     = (float*)(ws + 1752064);    // [4096,128] f32 -> ends 3,849,216
    __hip_bfloat16* bfc = (__hip_bfloat16*)(ws + 3849216);   // [224,960] -> ends 4,279,296
    // late-phase overlays (prior occupants dead):
    __hip_bfloat16* a2 = (__hip_bfloat16*)(ws + 4864);       // [4096,224] -> ends 1,839,872
    __hip_bfloat16* b2 = (__hip_bfloat16*)(ws + 1840128);    // [4032,224] -> ends 3,646,464
    // d_out scratch (65.5 MB; final GEMM reads only ws, rewrites all of d_out)
    __hip_bfloat16* pooled = (__hip_bfloat16*)((char*)d_out + 0);        // 7.86 MB
    float* fcout    = (float*)((char*)d_out + 8388608);                  // 3.67 MB
    int2*  ebuck    = (int2*) ((char*)d_out + 16777216);                 // 4096*96*8 = 3.1 MB
    float* aggc     = (float*)((char*)d_out + 25165824);                 // 1.6 MB

    // 1. zero {counter,flags,slotent,ecount,sums} || rank-1 precompute
    k_fillprep<<<59, 256, 0, stream>>>((float4*)counter, W_f, a_vec, R_w, wa1, wa2, rw);
    // 2. flags
    k_flags<<<16, 256, 0, stream>>>(x_batch, flags);
    // 3. compact slots || per-entity dots
    k_slotsent<<<12696, 256, 0, stream>>>(flags, counter, slotent, E_w, wa1, wa2, ha, ew);
    // 4. single-pass bucket scatter
    k_scatter96<<<3125, 256, 0, stream>>>(ei, etype, flags, ecount, ebuck);
    // 5. per-slot softmax-weighted aggregation (2-way edge split)
    k_agg<<<4096, 256, 0, stream>>>(counter, ecount, slotent, ebuck,
                                    E_w, R_w, ha, ew, rw, aggc);
    // 6. gather + project + elu + conv-u partial stats
    k_gatherconv<<<4096, 128, 0, stream>>>(x_batch, flags, aggc, W_f, conv_w,
                                           ebuf, gps, gpq, cpart);
    // 7. stat reductions -> A_c, B_c (bn1 folded in)
    k_redAB<<<32, 256, 0, stream>>>(gps, gpq, cpart, bn1_g, bn3_g, bn3_b, AB);
    // 8. conv recompute + fused affine + relu + pool
    k_pool<<<4096, 128, 0, stream>>>(ebuf, conv_w, AB, pooled);
    // 9. bfc repack (after ebuf death for b2 would matter, but b2 is written in step 10)
    k_padsbfc<<<840, 256, 0, stream>>>(fc_w, bfc);
    // 10. FC GEMM (y<7): BM=64, no bias, fused bn2 stats; b2 repack strips (y in 7..62)
    k_gemm_fc<<<dim3(64, 63), 256, 0, stream>>>(
        (const ushort_t*)pooled, (const ushort_t*)bfc, fcout, sums, T_w, b2);
    // 11. bn2 apply (scale/shift inline)
    k_bn2apply<<<3584, 256, 0, stream>>>(fcout, sums, bn2_g, bn2_b, a2);
    // 12. logits GEMM + sigmoid
    k_gemm_sig<KP, 4><<<dim3(32, 63), 256, 0, stream>>>(
        (const ushort_t*)a2, (const ushort_t*)b2, b_bias, out);
}

// Round 6
// 261.240 us; speedup vs baseline: 3.9081x; 1.1809x over previous
//
#include <hip/hip_runtime.h>
#include <hip/hip_bf16.h>
#include <math.h>

#define N_ENT   50000
#define N_REL   237
#define N_TYPE  4000
#define DE      100
#define NOUT    128
#define DT      200
#define N_EDGE  800000
#define B_SZ    4096
#define ALPHA   0.2f
#define EPS     1e-5f
#define NUM_FILT 32
#define CONV_W_OUT 60
#define POOL_W  30
#define FC_LEN  960
#define KP      224
#define NTP     4032   // logits N padded to 63*64
#define EBCAP   96     // max edges per slot (Poisson(16), max deg ~45 in 4k slots)

typedef unsigned short ushort_t;
typedef __attribute__((ext_vector_type(8))) short bf16x8;
typedef __attribute__((ext_vector_type(4))) float f32x4;

// ---------------- diagnostic fill (f32) ----------------
__global__ void k_fillconst(float* p, long n, float val) {
    long i = (long)blockIdx.x * blockDim.x + threadIdx.x;
    long stride = (long)gridDim.x * blockDim.x;
    for (; i < n; i += stride) p[i] = val;
}

// ------- merged: zero-fill (blocks 0..57) || wa1/wa2/rw precompute (block 58) -------
// zero region: flags[50000] + (dead slotent) + ecount[4096] + sums[448] = 234,560 B
#define ZERO_F4 14660
__global__ void k_fillprep(float4* zp, const float* Wf, const float* a_vec,
                           const float* Rw, float* wa1, float* wa2, float* rw) {
    if (blockIdx.x < 58) {
        int i = blockIdx.x * 256 + threadIdx.x;
        if (i < ZERO_F4) zp[i] = make_float4(0.f, 0.f, 0.f, 0.f);
        return;
    }
    __shared__ float sa[2 * NOUT];
    __shared__ float swa2[DE];
    int t = threadIdx.x;
    sa[t] = a_vec[t];
    __syncthreads();
    if (t < DE) {
        float s1 = 0.f, s2 = 0.f;
        for (int j = 0; j < NOUT; j++) {
            float w = Wf[t * NOUT + j];
            s1 += w * sa[j];
            s2 += w * sa[NOUT + j];
        }
        wa1[t] = s1; wa2[t] = s2; swa2[t] = s2;
    }
    __syncthreads();
    if (t < N_REL) {
        float s = 0.f;
        for (int k = 0; k < DE; k++) s += Rw[t * DE + k] * swa2[k];
        rw[t] = s;
    }
}

// ------- merged: direct-slot flags (blocks 0..15) || per-entity dots (16..) -------
// flags[xb[i]] = i+1 : plain store, benign race — any winning batch index is a
// valid bucket id; duplicates carry identical aggregation so output is invariant.
__global__ void k_flagsent(const int* xb, int* flags,
                           const float* Ew, const float* wa1, const float* wa2,
                           float* ha, float* ew) {
    if (blockIdx.x < 16) {
        int i = blockIdx.x * 256 + threadIdx.x;
        if (i < B_SZ) flags[xb[i]] = i + 1;
        return;
    }
    int wid = (blockIdx.x - 16) * 4 + (threadIdx.x >> 6);
    int lane = threadIdx.x & 63;
    if (wid >= N_ENT) return;
    float s1 = 0.f, s2 = 0.f;
    if (lane < DE / 2) {
        const float2* p = (const float2*)(Ew + (size_t)wid * DE);
        float2 v = p[lane];
        s1 = v.x * wa1[2 * lane] + v.y * wa1[2 * lane + 1];
        s2 = v.x * wa2[2 * lane] + v.y * wa2[2 * lane + 1];
    }
    for (int off = 32; off > 0; off >>= 1) {
        s1 += __shfl_down(s1, off);
        s2 += __shfl_down(s2, off);
    }
    if (lane == 0) { ha[wid] = s1; ew[wid] = s2; }
}

// ------- single-pass scatter into fixed-capacity buckets -------
__global__ void k_scatter96(const int* ei, const int* et, const int* flags,
                            int* ecount, int2* ebuck) {
    int e = blockIdx.x * blockDim.x + threadIdx.x;
    if (e >= N_EDGE) return;
    int s = flags[ei[N_EDGE + e]];
    if (!s) return;
    int idx = atomicAdd(&ecount[s - 1], 1);
    if (idx < EBCAP)
        ebuck[(size_t)(s - 1) * EBCAP + idx] = make_int2(ei[e], et[e]);
}

// ------- per-slot aggregation: 2 halves process alternate edges -------
// slot = batch index; entity = xb[slot]. Loser-dup / no-edge slots write zeros
// (n==0 -> acc=den=0), matching elu-input 0; those rows are never read anyway.
__global__ void k_agg(const int* xb, const int* ecount,
                      const int2* ebuck, const float* Ew, const float* Rw,
                      const float* ha, const float* ew, const float* rw,
                      float* aggc) {
    __shared__ float sacc[DE];
    __shared__ float sden;
    int slot = blockIdx.x;
    int t = threadIdx.x;          // 256
    int half = t >> 7;            // 0 or 1
    int tl = t & 127;
    int n = min(ecount[slot], EBCAP);
    const int2* eb = ebuck + (size_t)slot * EBCAP;
    float hae = ha[xb[slot]];
    float acc = 0.f, den = 0.f;
    for (int j = half; j < n; j += 2) {
        int2 p = eb[j];
        float sc = hae + ew[p.x] - rw[p.y];
        sc = sc >= 0.f ? sc : ALPHA * sc;
        float ex = expf(sc);
        den += ex;
        if (tl < DE) acc += ex * (Ew[(size_t)p.x * DE + tl] - Rw[(size_t)p.y * DE + tl]);
    }
    if (half == 1) {
        if (tl < DE) sacc[tl] = acc;
        if (tl == 0) sden = den;
    }
    __syncthreads();
    if (half == 0 && tl < DE) {
        float a = acc + sacc[tl];
        float d = den + sden;
        aggc[(size_t)slot * DE + tl] = a / (d + 1e-16f);
    }
}

// -------- gather + project + elu + conv-u partial stats (no atomics) --------
__global__ void k_gatherconv(const int* xb, const int* flags, const float* aggc,
                             const float* Wf, const float* convw,
                             float* ebuf, float* gps, float* gpq, float* cpart) {
    __shared__ float row[DE];
    __shared__ float xs[NOUT];
    __shared__ float cw[NUM_FILT * 9];
    __shared__ float red[NOUT], red2[NOUT];
    int b = blockIdx.x, t = threadIdx.x;
    int slot = flags[xb[b]] - 1;
    if (t < DE) row[t] = aggc[(size_t)slot * DE + t];
    for (int i = t; i < NUM_FILT * 9; i += 128) cw[i] = convw[i];
    __syncthreads();
    float acc = 0.f;
    for (int k = 0; k < DE; k++) acc += row[k] * Wf[k * NOUT + t];
    float x = acc > 0.f ? acc : expm1f(acc);
    xs[t] = x;
    ebuf[(size_t)b * NOUT + t] = x;
    red[t] = x; red2[t] = x * x;
    __syncthreads();
    for (int s = 64; s > 0; s >>= 1) {
        if (t < s) { red[t] += red[t + s]; red2[t] += red2[t + s]; }
        __syncthreads();
    }
    if (t == 0) { gps[b] = red[0]; gpq[b] = red2[0]; }
    int c = t >> 2, wg = t & 3;
    float ls = 0.f, lq = 0.f;
    for (int i = 0; i < 15; i++) {
        int w = wg + 4 * i;
        float u = 0.f;
        #pragma unroll
        for (int j = 0; j < 9; j++) u += cw[c * 9 + j] * xs[2 * w + j];
        ls += u; lq += u * u;
    }
    __syncthreads();
    red[t] = ls; red2[t] = lq;
    __syncthreads();
    if (wg == 0) {
        float s = red[t] + red[t + 1] + red[t + 2] + red[t + 3];
        float q = red2[t] + red2[t + 1] + red2[t + 2] + red2[t + 3];
        cpart[b * 64 + c] = s;
        cpart[b * 64 + 32 + c] = q;
    }
}

// ------- reduce stats per filter -> A_c, B_c -------
__global__ void k_redAB(const float* gps, const float* gpq, const float* cpart,
                        const float* g1, const float* g3, const float* b3, float* AB) {
    __shared__ float r1[256], r2[256], r3[256], r4[256];
    int c = blockIdx.x, t = threadIdx.x;
    float s = 0.f, q = 0.f, cs = 0.f, cq = 0.f;
    for (int b = t; b < B_SZ; b += 256) {
        s += gps[b]; q += gpq[b];
        cs += cpart[b * 64 + c]; cq += cpart[b * 64 + 32 + c];
    }
    r1[t] = s; r2[t] = q; r3[t] = cs; r4[t] = cq;
    __syncthreads();
    for (int k = 128; k > 0; k >>= 1) {
        if (t < k) { r1[t] += r1[t+k]; r2[t] += r2[t+k]; r3[t] += r3[t+k]; r4[t] += r4[t+k]; }
        __syncthreads();
    }
    if (t == 0) {
        float N1 = (float)(B_SZ * NOUT);
        float m1 = r1[0] / N1;
        float v1 = r2[0] / N1 - m1 * m1;
        float s1 = g1[0] * rsqrtf(v1 + EPS);
        float Nc = (float)(B_SZ * CONV_W_OUT);
        float mu = r3[0] / Nc;
        float vu = r4[0] / Nc - mu * mu;
        float A = g3[c] * s1 * rsqrtf(s1 * s1 * vu + EPS);
        AB[c] = A;
        AB[32 + c] = b3[c] - A * mu;
    }
}

// ------- merged: conv+pool (blocks 0..4095) || fc_w/T_w repacks (4096..) -------
__global__ void k_poolpads(const float* ebuf, const float* convw, const float* AB,
                           __hip_bfloat16* pooled, const float* fcw, const float* tw,
                           __hip_bfloat16* bfc, __hip_bfloat16* b2) {
    int t = threadIdx.x;   // 128
    if (blockIdx.x >= B_SZ) {
        int i = (blockIdx.x - B_SZ) * 128 + t;
        if (i < KP * FC_LEN) {
            bfc[i] = __float2bfloat16((i < DT * FC_LEN) ? fcw[i] : 0.f);
        } else {
            int j = i - KP * FC_LEN;
            if (j < NTP * KP) {
                int n = j / KP, k = j - n * KP;
                float v = (n < N_TYPE && k < DT) ? tw[n * DT + k] : 0.f;
                b2[j] = __float2bfloat16(v);
            }
        }
        return;
    }
    __shared__ float xs[NOUT];
    __shared__ float cw[NUM_FILT * 9];
    __shared__ float sA[32], sB[32];
    int b = blockIdx.x;
    xs[t] = ebuf[(size_t)b * NOUT + t];
    for (int i = t; i < NUM_FILT * 9; i += 128) cw[i] = convw[i];
    if (t < 32) { sA[t] = AB[t]; sB[t] = AB[32 + t]; }
    __syncthreads();
    int c = t >> 2, wg = t & 3;
    float A = sA[c], Bv = sB[c];
    for (int i = 0; i < 8; i++) {
        int w2 = wg + 4 * i;
        if (w2 < POOL_W) {
            int w = 2 * w2;
            float u0 = 0.f, u1 = 0.f;
            #pragma unroll
            for (int j = 0; j < 9; j++) {
                float cv = cw[c * 9 + j];
                u0 += cv * xs[2 * w + j];
                u1 += cv * xs[2 * w + 2 + j];
            }
            float z0 = fmaxf(A * u0 + Bv, 0.f);
            float z1 = fmaxf(A * u1 + Bv, 0.f);
            pooled[((size_t)b * NUM_FILT + c) * POOL_W + w2] = __float2bfloat16(fmaxf(z0, z1));
        }
    }
}

// ---------------- MFMA GEMM with swapped-operand transposed epilogue ----------------
// mfma(b, a, acc): lane&15 = output ROW, (lane>>4)*4+reg = 4 contiguous output COLS
// MODE 0: C = A@B^T + bias (f32). MODE 1: sigmoid(A@B^T + bias), guard cc < nbias.
template<int MODE, int K, int NB>
__launch_bounds__(256, 4)
__global__ void k_gemm(const ushort_t* A, const ushort_t* Bm, const float* bias,
                       int ldc, int nbias, float* Cf) {
    int wave = threadIdx.x >> 6, lane = threadIdx.x & 63;
    int m0 = blockIdx.x * 128 + wave * 32;
    int n0 = blockIdx.y * (16 * NB);
    int rsel = lane & 15, ksel = (lane >> 4) * 8;
    const ushort_t* pa0 = A + (size_t)(m0 + rsel) * K + ksel;
    const ushort_t* pa1 = pa0 + (size_t)16 * K;
    const ushort_t* pb[NB];
    #pragma unroll
    for (int j = 0; j < NB; j++) pb[j] = Bm + (size_t)(n0 + j * 16 + rsel) * K + ksel;
    f32x4 acc0[NB], acc1[NB];
    #pragma unroll
    for (int j = 0; j < NB; j++) { acc0[j] = (f32x4){0.f,0.f,0.f,0.f}; acc1[j] = acc0[j]; }
    if constexpr (K <= 256) {
        #pragma unroll
        for (int k = 0; k < K; k += 32) {
            bf16x8 a0 = *(const bf16x8*)(pa0 + k);
            bf16x8 a1 = *(const bf16x8*)(pa1 + k);
            #pragma unroll
            for (int j = 0; j < NB; j++) {
                bf16x8 b = *(const bf16x8*)(pb[j] + k);
                acc0[j] = __builtin_amdgcn_mfma_f32_16x16x32_bf16(b, a0, acc0[j], 0, 0, 0);
                acc1[j] = __builtin_amdgcn_mfma_f32_16x16x32_bf16(b, a1, acc1[j], 0, 0, 0);
            }
        }
    } else {
        #pragma unroll 4
        for (int k = 0; k < K; k += 32) {
            bf16x8 a0 = *(const bf16x8*)(pa0 + k);
            bf16x8 a1 = *(const bf16x8*)(pa1 + k);
            #pragma unroll
            for (int j = 0; j < NB; j++) {
                bf16x8 b = *(const bf16x8*)(pb[j] + k);
                acc0[j] = __builtin_amdgcn_mfma_f32_16x16x32_bf16(b, a0, acc0[j], 0, 0, 0);
                acc1[j] = __builtin_amdgcn_mfma_f32_16x16x32_bf16(b, a1, acc1[j], 0, 0, 0);
            }
        }
    }
    int mloc = lane & 15;
    int nq = (lane >> 4) * 4;
    #pragma unroll
    for (int j = 0; j < NB; j++) {
        int cc = n0 + j * 16 + nq;
        if (cc < nbias) {
            float4 bb = *(const float4*)(bias + cc);
            f32x4 v0 = acc0[j], v1 = acc1[j];
            float4 r0, r1;
            if (MODE == 0) {
                r0 = make_float4(v0[0] + bb.x, v0[1] + bb.y, v0[2] + bb.z, v0[3] + bb.w);
                r1 = make_float4(v1[0] + bb.x, v1[1] + bb.y, v1[2] + bb.z, v1[3] + bb.w);
            } else {
                r0.x = __builtin_amdgcn_rcpf(1.f + __expf(-(v0[0] + bb.x)));
                r0.y = __builtin_amdgcn_rcpf(1.f + __expf(-(v0[1] + bb.y)));
                r0.z = __builtin_amdgcn_rcpf(1.f + __expf(-(v0[2] + bb.z)));
                r0.w = __builtin_amdgcn_rcpf(1.f + __expf(-(v0[3] + bb.w)));
                r1.x = __builtin_amdgcn_rcpf(1.f + __expf(-(v1[0] + bb.x)));
                r1.y = __builtin_amdgcn_rcpf(1.f + __expf(-(v1[1] + bb.y)));
                r1.z = __builtin_amdgcn_rcpf(1.f + __expf(-(v1[2] + bb.z)));
                r1.w = __builtin_amdgcn_rcpf(1.f + __expf(-(v1[3] + bb.w)));
            }
            *(float4*)(Cf + (size_t)(m0 + mloc) * ldc + cc) = r0;
            *(float4*)(Cf + (size_t)(m0 + 16 + mloc) * ldc + cc) = r1;
        }
    }
}

// ------- bn2 partial sums: coalesced row panels, atomics into zeroed sums[448] -------
__global__ void k_bn2part(const float* fcout, float* sums) {
    int b = blockIdx.x, t = threadIdx.x;   // 32 blocks x 256 thr
    if (t >= DT) return;
    float s = 0.f, q = 0.f;
    const float* base = fcout + (size_t)b * 128 * KP + t;
    for (int r = 0; r < 128; r++) {
        float v = base[r * KP];
        s += v; q += v * v;
    }
    atomicAdd(&sums[t], s);
    atomicAdd(&sums[KP + t], q);
}

// ------- bn2 apply + relu -> bf16 A2 [B,224]; scale/shift derived inline -------
__global__ void k_bn2apply(const float* fcout, const float* sums,
                           const float* g, const float* bb, __hip_bfloat16* a2) {
    int i = blockIdx.x * blockDim.x + threadIdx.x;
    if (i >= B_SZ * KP) return;
    int t = i % KP;
    float v = 0.f;
    if (t < DT) {
        float mean = sums[t] * (1.f / B_SZ);
        float var = sums[KP + t] * (1.f / B_SZ) - mean * mean;
        float sc = g[t] * rsqrtf(var + EPS);
        float sh = bb[t] - mean * sc;
        v = fcout[i] * sc + sh;
        v = fmaxf(v, 0.f);
    }
    a2[i] = __float2bfloat16(v);
}

extern "C" void kernel_launch(void* const* d_in, const int* in_sizes, int n_in,
                              void* d_out, int out_size, void* d_ws, size_t ws_size,
                              hipStream_t stream) {
    (void)in_sizes; (void)n_in;
    const int*   x_batch = (const int*)d_in[0];
    const int*   ei      = (const int*)d_in[1];
    const int*   etype   = (const int*)d_in[2];
    const float* E_w     = (const float*)d_in[3];
    const float* R_w     = (const float*)d_in[4];
    const float* T_w     = (const float*)d_in[5];
    const float* W_f     = (const float*)d_in[6];
    const float* a_vec   = (const float*)d_in[7];
    const float* conv_w  = (const float*)d_in[8];
    const float* bn1_g   = (const float*)d_in[10];
    const float* bn3_g   = (const float*)d_in[12];
    const float* bn3_b   = (const float*)d_in[13];
    const float* bn2_g   = (const float*)d_in[14];
    const float* bn2_b   = (const float*)d_in[15];
    const float* fc_w    = (const float*)d_in[16];
    const float* fc_b    = (const float*)d_in[17];
    const float* b_bias  = (const float*)d_in[18];
    float* out           = (float*)d_out;
    long outn = (long)out_size;

    const size_t WS_NEEDED = 4279296;
    if (ws_size < WS_NEEDED) {
        k_fillconst<<<2048, 256, 0, stream>>>(out, outn, 50.f);
        return;
    }
    char* ws = (char*)d_ws;
    float* wa1      = (float*)(ws + 0);
    float* wa2      = (float*)(ws + 512);
    float* rw       = (float*)(ws + 1024);
    float* AB       = (float*)(ws + 2048);       // A[0..31], B[32..63]
    float* gps      = (float*)(ws + 4864);       // [4096]
    float* gpq      = (float*)(ws + 21248);      // [4096]
    float* cpart    = (float*)(ws + 37632);      // [4096][64] -> ends 1,086,208
    int*   flags    = (int*)  (ws + 1086464);    // [50000] -> zero-region start
    int*   ecount   = (int*)  (ws + 1302848);    // [4096]
    float* sums     = (float*)(ws + 1319232);    // [448] -> zero-region ends 1,321,024
    float* ha       = (float*)(ws + 1352064);    // [50000]
    float* ew       = (float*)(ws + 1552064);    // [50000]
    float* ebuf     = (float*)(ws + 1752064);    // [4096,128] f32 -> ends 3,849,216
    __hip_bfloat16* bfc = (__hip_bfloat16*)(ws + 3849216);   // [224,960] -> ends 4,279,296
    // late-phase overlays (prior occupants dead):
    __hip_bfloat16* a2 = (__hip_bfloat16*)(ws + 4864);       // [4096,224] -> ends 1,839,872
    __hip_bfloat16* b2 = (__hip_bfloat16*)(ws + 1840128);    // [4032,224] -> ends 3,646,464
    // d_out scratch (65.5 MB; final GEMM reads only ws, rewrites all of d_out)
    __hip_bfloat16* pooled = (__hip_bfloat16*)((char*)d_out + 0);        // 7.86 MB
    float* fcout    = (float*)((char*)d_out + 8388608);                  // 3.67 MB
    int2*  ebuck    = (int2*) ((char*)d_out + 16777216);                 // 4096*96*8 = 3.1 MB
    float* aggc     = (float*)((char*)d_out + 25165824);                 // 1.6 MB

    // 1. zero {flags,ecount,sums} || rank-1 precompute
    k_fillprep<<<59, 256, 0, stream>>>((float4*)flags, W_f, a_vec, R_w, wa1, wa2, rw);
    // 2. direct-slot flags || per-entity dots
    k_flagsent<<<12516, 256, 0, stream>>>(x_batch, flags, E_w, wa1, wa2, ha, ew);
    // 3. single-pass bucket scatter
    k_scatter96<<<3125, 256, 0, stream>>>(ei, etype, flags, ecount, ebuck);
    // 4. per-slot softmax-weighted aggregation (2-way edge split)
    k_agg<<<4096, 256, 0, stream>>>(x_batch, ecount, ebuck,
                                    E_w, R_w, ha, ew, rw, aggc);
    // 5. gather + project + elu + conv-u partial stats
    k_gatherconv<<<4096, 128, 0, stream>>>(x_batch, flags, aggc, W_f, conv_w,
                                           ebuf, gps, gpq, cpart);
    // 6. stat reductions -> A_c, B_c (bn1 folded in)
    k_redAB<<<32, 256, 0, stream>>>(gps, gpq, cpart, bn1_g, bn3_g, bn3_b, AB);
    // 7. conv recompute + affine + relu + pool || fc_w/T_w repacks
    k_poolpads<<<12832, 128, 0, stream>>>(ebuf, conv_w, AB, pooled, fc_w, T_w, bfc, b2);
    // 8. FC GEMM: K=960, NB=2 -> fcout f32 [4096,224]
    k_gemm<0, FC_LEN, 2><<<dim3(32, 7), 256, 0, stream>>>(
        (const ushort_t*)pooled, (const ushort_t*)bfc, fc_b, KP, DT, fcout);
    // 9. bn2 partial sums (coalesced)
    k_bn2part<<<32, 256, 0, stream>>>(fcout, sums);
    // 10. bn2 apply (scale/shift inline)
    k_bn2apply<<<3584, 256, 0, stream>>>(fcout, sums, bn2_g, bn2_b, a2);
    // 11. logits GEMM + sigmoid
    k_gemm<1, KP, 4><<<dim3(32, 63), 256, 0, stream>>>(
        (const ushort_t*)a2, (const ushort_t*)b2, b_bias, N_TYPE, N_TYPE, out);
}